// Round 1
// baseline (306.444 us; speedup 1.0000x reference)
//
#include <hip/hip_runtime.h>

// SUBGRAPH_5231270167316
// Reference needs only score[:, :2, :]:
//   score[b,i,j] = (dot(s_e[b,i,j,:], W[:,0]) + b[0]) * adj'[b,i,j],  i in {0,1}
//   adj' = adj with [b,0,1]=0 and [b,1,0]=0
//   sub_id[b] = argmax_j score[b,0,j]  (first occurrence, numpy semantics)
//   obj_id[b] = argmax_j score[b,1,j]
//   outputs (flat fp32): final_id (B,2) || s_e_score (B,2,N) || flag (B)

#define BB 32
#define NN 64
#define DD 512

__global__ __launch_bounds__(1024) void subgraph_kernel(
    const float* __restrict__ s_e,
    const float* __restrict__ adj,
    const float* __restrict__ W,
    const float* __restrict__ bias,
    float* __restrict__ out)
{
    const int b    = blockIdx.x;
    const int tid  = threadIdx.x;
    const int wave = tid >> 6;   // 0..15
    const int lane = tid & 63;

    __shared__ float scores[2][NN];
    __shared__ int   ids[2];

    // Each lane owns W[lane*8 .. lane*8+8) for the whole kernel.
    const float4 w0 = *reinterpret_cast<const float4*>(W + lane * 8);
    const float4 w1 = *reinterpret_cast<const float4*>(W + lane * 8 + 4);
    const float  b0 = bias[0];

    // 2*NN = 128 (i,j) pairs; 16 waves -> 8 pairs per wave.
    for (int p = wave; p < 2 * NN; p += 16) {
        const int i = p >> 6;
        const int j = p & 63;
        const float* base =
            s_e + (((size_t)b * NN + i) * NN + j) * DD + lane * 8;
        const float4 a0 = *reinterpret_cast<const float4*>(base);
        const float4 a1 = *reinterpret_cast<const float4*>(base + 4);
        float s = a0.x * w0.x + a0.y * w0.y + a0.z * w0.z + a0.w * w0.w
                + a1.x * w1.x + a1.y * w1.y + a1.z * w1.z + a1.w * w1.w;
        // wave-64 butterfly sum
        #pragma unroll
        for (int off = 32; off; off >>= 1)
            s += __shfl_xor(s, off, 64);
        if (lane == 0) {
            float a = adj[((size_t)b * NN + i) * NN + j];
            if ((i == 0 && j == 1) || (i == 1 && j == 0)) a = 0.0f;
            scores[i][j] = (s + b0) * a;
        }
    }
    __syncthreads();

    // First-occurrence argmax (exact numpy semantics: strict > scan).
    if (tid < 2) {
        const int i = tid;
        float best  = scores[i][0];
        int   bestj = 0;
        for (int j = 1; j < NN; ++j) {
            const float v = scores[i][j];
            if (v > best) { best = v; bestj = j; }
        }
        ids[i] = bestj;
        out[b * 2 + i] = (float)bestj;   // final_id as float
    }
    __syncthreads();

    // s_e_score: 128 floats per batch
    if (tid < 128) {
        out[BB * 2 + b * 128 + tid] = scores[tid >> 6][tid & 63];
    }
    // flag
    if (tid == 0) {
        const bool sp = ids[0] > 0;
        const bool op = ids[1] > 0;
        const float flag = (sp && op) ? 3.0f : (sp ? 1.0f : (op ? 2.0f : 0.0f));
        out[BB * 2 + BB * 2 * NN + b] = flag;
    }
}

extern "C" void kernel_launch(void* const* d_in, const int* in_sizes, int n_in,
                              void* d_out, int out_size, void* d_ws, size_t ws_size,
                              hipStream_t stream) {
    const float* s_e  = (const float*)d_in[0];
    const float* adj  = (const float*)d_in[1];
    const float* W    = (const float*)d_in[2];
    const float* bias = (const float*)d_in[3];
    float* out = (float*)d_out;

    subgraph_kernel<<<BB, 1024, 0, stream>>>(s_e, adj, W, bias, out);
}

// Round 2
// 301.528 us; speedup vs baseline: 1.0163x; 1.0163x over previous
//
#include <hip/hip_runtime.h>

// SUBGRAPH_5231270167316
// Only score[:, :2, :] matters:
//   score[b,i,j] = (dot(s_e[b,i,j,:], W[:,0]) + b[0]) * adj'[b,i,j], i in {0,1}
//   adj' = adj with [b,0,1]=0, [b,1,0]=0
//   ids = first-occurrence argmax over j (strict >, numpy semantics)
// Output (flat fp32): final_id (B,2)=64 || s_e_score (B,2,N)=4096 || flag (B)=32

#define BB 32
#define NN 64
#define DD 512

// One block per (b,i): 64 blocks, 1024 threads = 16 waves, 4 j's per wave.
__global__ __launch_bounds__(1024) void score_kernel(
    const float* __restrict__ s_e,
    const float* __restrict__ adj,
    const float* __restrict__ W,
    const float* __restrict__ bias,
    float* __restrict__ out)
{
    const int bi   = blockIdx.x;       // 0..63
    const int b    = bi >> 1;
    const int i    = bi & 1;
    const int tid  = threadIdx.x;
    const int wave = tid >> 6;         // 0..15
    const int lane = tid & 63;

    __shared__ float scores[NN];

    const float4 w0 = *reinterpret_cast<const float4*>(W + lane * 8);
    const float4 w1 = *reinterpret_cast<const float4*>(W + lane * 8 + 4);
    const float  b0 = bias[0];

    const float* rowbase = s_e + (((size_t)b * NN + i) * NN) * DD + lane * 8;

    // Issue all 8 loads up front (4 j's x 2 float4) for max MLP overlap.
    float4 a[4][2];
    #pragma unroll
    for (int k = 0; k < 4; ++k) {
        const int j = wave + 16 * k;
        a[k][0] = *reinterpret_cast<const float4*>(rowbase + (size_t)j * DD);
        a[k][1] = *reinterpret_cast<const float4*>(rowbase + (size_t)j * DD + 4);
    }

    float s[4];
    #pragma unroll
    for (int k = 0; k < 4; ++k) {
        // Identical per-lane sum order to the verified R1 kernel.
        s[k] = a[k][0].x * w0.x + a[k][0].y * w0.y + a[k][0].z * w0.z + a[k][0].w * w0.w
             + a[k][1].x * w1.x + a[k][1].y * w1.y + a[k][1].z * w1.z + a[k][1].w * w1.w;
    }

    // Four independent butterfly reduces (identical order to R1); compiler
    // interleaves them to hide shuffle latency.
    #pragma unroll
    for (int off = 32; off; off >>= 1) {
        #pragma unroll
        for (int k = 0; k < 4; ++k)
            s[k] += __shfl_xor(s[k], off, 64);
    }

    if (lane == 0) {
        #pragma unroll
        for (int k = 0; k < 4; ++k) {
            const int j = wave + 16 * k;
            float av = adj[((size_t)b * NN + i) * NN + j];
            if ((i == 0 && j == 1) || (i == 1 && j == 0)) av = 0.0f;
            scores[j] = (s[k] + b0) * av;
        }
    }
    __syncthreads();

    // s_e_score slice for this (b,i)
    if (tid < NN)
        out[BB * 2 + (size_t)bi * NN + tid] = scores[tid];

    // First-occurrence argmax, strict > (numpy semantics).
    if (tid == 0) {
        float best  = scores[0];
        int   bestj = 0;
        for (int j = 1; j < NN; ++j) {
            const float v = scores[j];
            if (v > best) { best = v; bestj = j; }
        }
        out[bi] = (float)bestj;   // final_id as float
    }
}

// Tiny pass: flag[b] from the two id floats (same-stream ordering after score_kernel).
__global__ void flag_kernel(float* __restrict__ out)
{
    const int b = threadIdx.x;
    if (b < BB) {
        const bool sp = out[b * 2]     > 0.5f;
        const bool op = out[b * 2 + 1] > 0.5f;
        out[BB * 2 + BB * 2 * NN + b] =
            (sp && op) ? 3.0f : (sp ? 1.0f : (op ? 2.0f : 0.0f));
    }
}

extern "C" void kernel_launch(void* const* d_in, const int* in_sizes, int n_in,
                              void* d_out, int out_size, void* d_ws, size_t ws_size,
                              hipStream_t stream) {
    const float* s_e  = (const float*)d_in[0];
    const float* adj  = (const float*)d_in[1];
    const float* W    = (const float*)d_in[2];
    const float* bias = (const float*)d_in[3];
    float* out = (float*)d_out;

    score_kernel<<<BB * 2, 1024, 0, stream>>>(s_e, adj, W, bias, out);
    flag_kernel<<<1, 64, 0, stream>>>(out);
}